// Round 1
// 626.611 us; speedup vs baseline: 1.2253x; 1.2253x over previous
//
#include <hip/hip_runtime.h>
#include <hip/hip_bf16.h>

// GCN forward, CSR-gather formulation, gather+GEMM FUSED.
// k_fused1: gather x over edges (78 feats) -> per-wave LDS -> GEMM W1 -> relu -> h1
// k_fused2: gather h1 over edges (128 feats) -> per-wave LDS -> GEMM W2 -> relu
//           -> pre-reduced segment-max pool (batch sorted).
// Rationale: gathers are HBM-bound (VALUBusy 15%), GEMMs are VALU-bound; fusing
// hides GEMM under gather stalls and kills the agg1/agg2 HBM round-trips
// (~170 MB). W is NOT LDS-staged (wave-uniform/coalesced loads from L1/L2) so
// LDS stays at 10-16 KB/block and occupancy stays high for latency hiding.

#define NN 100000
#define NE 1600000
#define NG 512
#define NBLK ((NN + 1023) / 1024)   // 98 scan blocks

// ---------------- CSR build (counting sort by dst) ----------------

__global__ void k_zero_int(int* p, int n) {
    int i = blockIdx.x * blockDim.x + threadIdx.x;
    if (i < n) p[i] = 0;
}

__global__ void k_hist(const int* __restrict__ dst, int* cnt, int e) {
    int i = blockIdx.x * blockDim.x + threadIdx.x;
    if (i < e) atomicAdd(&cnt[dst[i]], 1);
}

// fused: dinv[i] = rsqrt(cnt[i]+1)  and  gmax zero-init (NG*256 = 131072)
__global__ void k_prep(const int* __restrict__ cnt, float* __restrict__ dinv,
                       float* __restrict__ gmax) {
    int i = blockIdx.x * blockDim.x + threadIdx.x;
    if (i < NN) dinv[i] = rsqrtf((float)cnt[i] + 1.0f);
    if (i < NG * 256) gmax[i] = 0.0f;
}

__global__ __launch_bounds__(256) void k_bsum(const int* __restrict__ cnt, int* __restrict__ bsum) {
    __shared__ int s[256];
    int b = blockIdx.x, t = threadIdx.x;
    int base = b * 1024 + t * 4;
    int v = 0;
#pragma unroll
    for (int j = 0; j < 4; j++) { int i = base + j; if (i < NN) v += cnt[i]; }
    s[t] = v; __syncthreads();
    for (int off = 128; off > 0; off >>= 1) {
        if (t < off) s[t] += s[t + off];
        __syncthreads();
    }
    if (t == 0) bsum[b] = s[0];
}

__global__ __launch_bounds__(128) void k_scan_bsum(int* bsum, int* row_ptr) {
    __shared__ int s[128];
    int t = threadIdx.x;
    int v = (t < NBLK) ? bsum[t] : 0;
    s[t] = v; __syncthreads();
    for (int off = 1; off < 128; off <<= 1) {
        int u = (t >= off) ? s[t - off] : 0;
        __syncthreads();
        s[t] += u;
        __syncthreads();
    }
    if (t < NBLK) bsum[t] = s[t] - v;
    if (t == 0) row_ptr[NN] = NE;
}

__global__ __launch_bounds__(256) void k_scan_blocks(const int* __restrict__ cnt,
    const int* __restrict__ bsum, int* __restrict__ row_ptr, int* __restrict__ cursor) {
    __shared__ int s[256];
    int b = blockIdx.x, t = threadIdx.x;
    int base = b * 1024 + t * 4;
    int v[4]; int sum = 0;
#pragma unroll
    for (int j = 0; j < 4; j++) { int i = base + j; v[j] = (i < NN) ? cnt[i] : 0; sum += v[j]; }
    s[t] = sum; __syncthreads();
    for (int off = 1; off < 256; off <<= 1) {
        int u = (t >= off) ? s[t - off] : 0;
        __syncthreads();
        s[t] += u;
        __syncthreads();
    }
    int excl = s[t] - sum + bsum[b];
#pragma unroll
    for (int j = 0; j < 4; j++) {
        int i = base + j;
        if (i < NN) { row_ptr[i] = excl; cursor[i] = excl; excl += v[j]; }
    }
}

// counting-sort fill: one packed 8B store per edge: es[pos] = {src, w}
__global__ void k_fillslots(const int* __restrict__ src, const int* __restrict__ dst,
    const float* __restrict__ dinv, int* cursor, int2* __restrict__ es, int e) {
    int i = blockIdx.x * blockDim.x + threadIdx.x;
    if (i >= e) return;
    int s = src[i], d = dst[i];
    int pos = atomicAdd(&cursor[d], 1);
    es[pos] = make_int2(s, __float_as_int(dinv[s] * dinv[d]));
}

// ---------------- fused1: gather78 + gemm1 ----------------
// 4 waves/block, wave owns 8 nodes. Gather each node's 78 feats (lanes 0..38,
// float2) with 8-deep pipelined edge loop into LDS row (stride 80 for float4
// alignment). Then GEMM: lane covers 2 of 128 out-feats; A wave-uniform from
// LDS (broadcast); W1 rows coalesced from L1/L2 (40 KB, L2-resident).
__global__ __launch_bounds__(256) void k_fused1(const float* __restrict__ x,
    const int* __restrict__ rp, const int2* __restrict__ es,
    const float* __restrict__ dinv, const float* __restrict__ W,
    const float* __restrict__ bias, float* __restrict__ out) {
    __shared__ float As[4][8][80];   // 10 KB
    int tid = threadIdx.x;
    int wv = tid >> 6, l = tid & 63;
    int task = __builtin_amdgcn_readfirstlane(blockIdx.x * 4 + wv);  // 12500 tasks
    int n0 = task * 8;

    for (int i = 0; i < 8; i++) {
        if (l < 39) {
            int n = n0 + i;
            float di = dinv[n], sw = di * di;
            float2 a = ((const float2*)(x + (size_t)n * 78))[l];
            a.x *= sw; a.y *= sw;
            int e = rp[n], e1 = rp[n + 1];
            int nf = (e1 - e) >> 3;
            if (nf > 0) {
                int2 cur[8];
#pragma unroll
                for (int j = 0; j < 8; j++) cur[j] = es[e + j];
                for (int b = 1; ; b++) {
                    float2 v[8];
#pragma unroll
                    for (int j = 0; j < 8; j++)
                        v[j] = ((const float2*)(x + (size_t)cur[j].x * 78))[l];
                    e += 8;
                    bool more = (b < nf);
                    int2 nxt[8];
                    if (more) {
#pragma unroll
                        for (int j = 0; j < 8; j++) nxt[j] = es[e + j];
                    }
#pragma unroll
                    for (int j = 0; j < 8; j++) {
                        float w = __int_as_float(cur[j].y);
                        a.x += v[j].x * w; a.y += v[j].y * w;
                    }
                    if (!more) break;
#pragma unroll
                    for (int j = 0; j < 8; j++) cur[j] = nxt[j];
                }
            }
            for (; e < e1; e++) {
                int2 p = es[e];
                float w = __int_as_float(p.y);
                float2 v = ((const float2*)(x + (size_t)p.x * 78))[l];
                a.x += v.x * w; a.y += v.y * w;
            }
            *(float2*)&As[wv][i][2 * l] = a;
        }
    }
    // same-wave producer/consumer: compiler inserts lgkmcnt waits; no barrier.

    int f0 = l * 2;
    float2 acc[8];
#pragma unroll
    for (int i = 0; i < 8; i++) acc[i] = make_float2(0.f, 0.f);

    for (int k = 0; k < 76; k += 4) {
        float2 w0 = *(const float2*)&W[(k + 0) * 128 + f0];
        float2 w1 = *(const float2*)&W[(k + 1) * 128 + f0];
        float2 w2 = *(const float2*)&W[(k + 2) * 128 + f0];
        float2 w3 = *(const float2*)&W[(k + 3) * 128 + f0];
#pragma unroll
        for (int i = 0; i < 8; i++) {
            float4 a = *(const float4*)&As[wv][i][k];
            acc[i].x += a.x * w0.x + a.y * w1.x + a.z * w2.x + a.w * w3.x;
            acc[i].y += a.x * w0.y + a.y * w1.y + a.z * w2.y + a.w * w3.y;
        }
    }
    {   // rows 76,77
        float2 w0 = *(const float2*)&W[76 * 128 + f0];
        float2 w1 = *(const float2*)&W[77 * 128 + f0];
#pragma unroll
        for (int i = 0; i < 8; i++) {
            float2 a = *(const float2*)&As[wv][i][76];
            acc[i].x += a.x * w0.x + a.y * w1.x;
            acc[i].y += a.x * w0.y + a.y * w1.y;
        }
    }
    float2 bv = *(const float2*)&bias[f0];
#pragma unroll
    for (int i = 0; i < 8; i++) {
        float2 o;
        o.x = fmaxf(acc[i].x + bv.x, 0.f);
        o.y = fmaxf(acc[i].y + bv.y, 0.f);
        *(float2*)&out[(size_t)(n0 + i) * 128 + f0] = o;
    }
}

// ---------------- fused2: gather128 + gemm2 + pool ----------------
// 4 waves/block, wave owns 8 nodes. Gather 128 feats (all 64 lanes, float2)
// into LDS; GEMM: lane covers 4 of 256 out-feats; W2 rows (1 KB) coalesced
// from L2. Pool: flush-on-change segment-max (batch sorted) with atomicMax.
__global__ __launch_bounds__(256) void k_fused2(const float* __restrict__ h,
    const int* __restrict__ rp, const int2* __restrict__ es,
    const float* __restrict__ dinv, const float* __restrict__ W,
    const float* __restrict__ bias, const int* __restrict__ batch,
    unsigned* __restrict__ gmax) {
    __shared__ float As[4][8][128];  // 16 KB
    int tid = threadIdx.x;
    int wv = tid >> 6, l = tid & 63;
    int task = __builtin_amdgcn_readfirstlane(blockIdx.x * 4 + wv);  // 12500 tasks
    int n0 = task * 8;

    for (int i = 0; i < 8; i++) {
        int n = n0 + i;
        float di = dinv[n], sw = di * di;
        float2 a = ((const float2*)(h + (size_t)n * 128))[l];
        a.x *= sw; a.y *= sw;
        int e = rp[n], e1 = rp[n + 1];
        int nf = (e1 - e) >> 3;
        if (nf > 0) {
            int2 cur[8];
#pragma unroll
            for (int j = 0; j < 8; j++) cur[j] = es[e + j];
            for (int b = 1; ; b++) {
                float2 v[8];
#pragma unroll
                for (int j = 0; j < 8; j++)
                    v[j] = ((const float2*)(h + (size_t)cur[j].x * 128))[l];
                e += 8;
                bool more = (b < nf);
                int2 nxt[8];
                if (more) {
#pragma unroll
                    for (int j = 0; j < 8; j++) nxt[j] = es[e + j];
                }
#pragma unroll
                for (int j = 0; j < 8; j++) {
                    float w = __int_as_float(cur[j].y);
                    a.x += v[j].x * w; a.y += v[j].y * w;
                }
                if (!more) break;
#pragma unroll
                for (int j = 0; j < 8; j++) cur[j] = nxt[j];
            }
        }
        for (; e < e1; e++) {
            int2 p = es[e];
            float w = __int_as_float(p.y);
            float2 v = ((const float2*)(h + (size_t)p.x * 128))[l];
            a.x += v.x * w; a.y += v.y * w;
        }
        *(float2*)&As[wv][i][2 * l] = a;
    }
    // same-wave producer/consumer: no barrier needed.

    int f0 = l * 4;
    float4 acc[8];
#pragma unroll
    for (int i = 0; i < 8; i++) acc[i] = make_float4(0.f, 0.f, 0.f, 0.f);

    for (int k = 0; k < 128; k += 4) {
        float4 w0 = *(const float4*)&W[(size_t)(k + 0) * 256 + f0];
        float4 w1 = *(const float4*)&W[(size_t)(k + 1) * 256 + f0];
        float4 w2 = *(const float4*)&W[(size_t)(k + 2) * 256 + f0];
        float4 w3 = *(const float4*)&W[(size_t)(k + 3) * 256 + f0];
#pragma unroll
        for (int i = 0; i < 8; i++) {
            float4 a = *(const float4*)&As[wv][i][k];
            acc[i].x += a.x * w0.x + a.y * w1.x + a.z * w2.x + a.w * w3.x;
            acc[i].y += a.x * w0.y + a.y * w1.y + a.z * w2.y + a.w * w3.y;
            acc[i].z += a.x * w0.z + a.y * w1.z + a.z * w2.z + a.w * w3.z;
            acc[i].w += a.x * w0.w + a.y * w1.w + a.z * w2.w + a.w * w3.w;
        }
    }

    float4 bv = *(const float4*)&bias[f0];
    int curg = -1;
    float4 m = make_float4(0.f, 0.f, 0.f, 0.f);
#pragma unroll
    for (int i = 0; i < 8; i++) {
        int g = batch[n0 + i];
        float4 v;
        v.x = fmaxf(acc[i].x + bv.x, 0.f); v.y = fmaxf(acc[i].y + bv.y, 0.f);
        v.z = fmaxf(acc[i].z + bv.z, 0.f); v.w = fmaxf(acc[i].w + bv.w, 0.f);
        if (g != curg) {
            if (curg >= 0) {
                unsigned* gp = &gmax[(size_t)curg * 256 + f0];
                atomicMax(&gp[0], __float_as_uint(m.x));
                atomicMax(&gp[1], __float_as_uint(m.y));
                atomicMax(&gp[2], __float_as_uint(m.z));
                atomicMax(&gp[3], __float_as_uint(m.w));
            }
            curg = g; m = v;
        } else {
            m.x = fmaxf(m.x, v.x); m.y = fmaxf(m.y, v.y);
            m.z = fmaxf(m.z, v.z); m.w = fmaxf(m.w, v.w);
        }
    }
    if (curg >= 0) {
        unsigned* gp = &gmax[(size_t)curg * 256 + f0];
        atomicMax(&gp[0], __float_as_uint(m.x));
        atomicMax(&gp[1], __float_as_uint(m.y));
        atomicMax(&gp[2], __float_as_uint(m.z));
        atomicMax(&gp[3], __float_as_uint(m.w));
    }
}

// ---------------- MLP head ----------------

__global__ __launch_bounds__(256) void k_gemm3(const float* __restrict__ A,
    const float* __restrict__ W, const float* __restrict__ bias,
    float* __restrict__ out) {
    __shared__ float rs[256];
    int g = blockIdx.x, tid = threadIdx.x;
    rs[tid] = A[g * 256 + tid];
    __syncthreads();
    float acc[4] = {0.f, 0.f, 0.f, 0.f};
    for (int k = 0; k < 256; k++) {
        float a = rs[k];
#pragma unroll
        for (int j = 0; j < 4; j++) acc[j] += a * W[k * 1024 + tid + j * 256];
    }
#pragma unroll
    for (int j = 0; j < 4; j++) {
        int f = tid + j * 256;
        out[g * 1024 + f] = fmaxf(acc[j] + bias[f], 0.0f);
    }
}

__global__ __launch_bounds__(128) void k_gemm4(const float* __restrict__ A,
    const float* __restrict__ W, const float* __restrict__ bias,
    float* __restrict__ out) {
    __shared__ float rs[1024];
    int g = blockIdx.x, tid = threadIdx.x;
    for (int i = tid; i < 1024; i += 128) rs[i] = A[g * 1024 + i];
    __syncthreads();
    float acc = 0.0f;
    for (int k = 0; k < 1024; k++) acc += rs[k] * W[k * 128 + tid];
    out[g * 128 + tid] = acc + bias[tid];
}

extern "C" void kernel_launch(void* const* d_in, const int* in_sizes, int n_in,
                              void* d_out, int out_size, void* d_ws, size_t ws_size,
                              hipStream_t stream) {
    const float* x    = (const float*)d_in[0];
    const int*   ei   = (const int*)d_in[1];
    const int*   batch= (const int*)d_in[2];
    const float* W1   = (const float*)d_in[3];
    const float* b1   = (const float*)d_in[4];
    const float* W2   = (const float*)d_in[5];
    const float* b2   = (const float*)d_in[6];
    const float* Wg1  = (const float*)d_in[7];
    const float* bg1  = (const float*)d_in[8];
    const float* Wg2  = (const float*)d_in[9];
    const float* bg2  = (const float*)d_in[10];
    const int* src = ei;
    const int* dst = ei + NE;

    char* w8 = (char*)d_ws;
    int*   cnt     = (int*)w8;                 w8 += (size_t)NN * 4;
    int*   row_ptr = (int*)w8;                 w8 += (size_t)(NN + 4) * 4;
    int*   cursor  = (int*)w8;                 w8 += (size_t)NN * 4;
    int*   bsum    = (int*)w8;                 w8 += 128 * 4;
    int2*  es      = (int2*)w8;                w8 += (size_t)NE * 8;
    float* dinv    = (float*)w8;               w8 += (size_t)NN * 4;
    float* h1      = (float*)w8;               w8 += (size_t)NN * 128 * 4;
    unsigned* gmax = (unsigned*)w8;            w8 += (size_t)NG * 256 * 4;
    float* g1      = (float*)w8;               w8 += (size_t)NG * 1024 * 4;

    // CSR build
    k_zero_int<<<(NN + 255) / 256, 256, 0, stream>>>(cnt, NN);
    k_hist<<<(NE + 255) / 256, 256, 0, stream>>>(dst, cnt, NE);
    k_prep<<<(NG * 256 + 255) / 256, 256, 0, stream>>>(cnt, dinv, (float*)gmax);
    k_bsum<<<NBLK, 256, 0, stream>>>(cnt, bsum);
    k_scan_bsum<<<1, 128, 0, stream>>>(bsum, row_ptr);
    k_scan_blocks<<<NBLK, 256, 0, stream>>>(cnt, bsum, row_ptr, cursor);
    k_fillslots<<<(NE + 255) / 256, 256, 0, stream>>>(src, dst, dinv, cursor, es, NE);

    // layer 1 (fused gather + gemm + relu)
    k_fused1<<<NN / 32, 256, 0, stream>>>(x, row_ptr, es, dinv, W1, b1, h1);

    // layer 2 (fused gather + gemm + relu + pool)
    k_fused2<<<NN / 32, 256, 0, stream>>>(h1, row_ptr, es, dinv, W2, b2, batch, gmax);

    // MLP head
    k_gemm3<<<NG, 256, 0, stream>>>((const float*)gmax, Wg1, bg1, g1);
    k_gemm4<<<NG, 128, 0, stream>>>(g1, Wg2, bg2, (float*)d_out);
}